// Round 18
// baseline (149.491 us; speedup 1.0000x reference)
//
#include <hip/hip_runtime.h>
#include <hip/hip_bf16.h>
#include <math.h>

typedef __bf16 bf16x8 __attribute__((ext_vector_type(8)));
typedef float  f32x4  __attribute__((ext_vector_type(4)));
typedef float  f32x4v __attribute__((ext_vector_type(4)));
typedef unsigned short ushort_t;
typedef ushort_t u16x4 __attribute__((ext_vector_type(4)));
typedef ushort_t u16x8 __attribute__((ext_vector_type(8)));

__device__ __forceinline__ ushort_t f2bf(float f) {
    unsigned u = __builtin_bit_cast(unsigned, f);
    u += 0x7FFFu + ((u >> 16) & 1u);
    return (ushort_t)(u >> 16);
}

// XCD-aware bijective remap (m157/m204). Requires total grid % 8 == 0.
__device__ __forceinline__ void xcd_remap(int& bx, int& by, int& bz) {
    const int gx = gridDim.x, gy = gridDim.y;
    const int nwg = gx * gy * gridDim.z;
    const int lin = (blockIdx.z * gy + blockIdx.y) * gx + blockIdx.x;
    const int chunk = nwg >> 3;
    int nid = (lin & 7) * chunk + (lin >> 3);
    bx = nid % gx; nid /= gx;
    by = nid % gy; bz = nid / gy;
}

// ---- merged prep launch: cvt v (6144 blocks) + 4 weights (4x576) ----
__global__ __launch_bounds__(256)
void cvt_all(const float* __restrict__ v, const float* __restrict__ Wq,
             const float* __restrict__ Wk, const float* __restrict__ Wv,
             const float* __restrict__ Wp,
             ushort_t* __restrict__ vb, ushort_t* __restrict__ Wqb,
             ushort_t* __restrict__ Wkb, ushort_t* __restrict__ Wvb,
             ushort_t* __restrict__ Wpb)
{
    const int b = blockIdx.x;
    if (b < 6144) {
        int i = b * 256 + threadIdx.x;
        f32x4v x = ((const f32x4v*)v)[i];
        u16x4 o = { f2bf(x.x), f2bf(x.y), f2bf(x.z), f2bf(x.w) };
        ((u16x4*)vb)[i] = o;
    } else {
        const int w = (b - 6144) / 576;
        const int bb = (b - 6144) % 576;
        const float* in  = w == 0 ? Wq : w == 1 ? Wk : w == 2 ? Wv : Wp;
        ushort_t*    out = w == 0 ? Wqb : w == 1 ? Wkb : w == 2 ? Wvb : Wpb;
        int i = bb * 256 + threadIdx.x;
        f32x4v x = ((const f32x4v*)in)[i];
        u16x4 o = { f2bf(x.x), f2bf(x.y), f2bf(x.z), f2bf(x.w) };
        ((u16x4*)out)[i] = o;
    }
}

// ============================================================================
// 256x256 / BK=64 / 8-wave 2-PHASE core (round-6 proven). T2 swizzle applied
// inverse-on-source (linear gload_lds dest, rule #21), T5 setprio.
// ============================================================================
#define GEMM256_CORE(Ab_, lda_, Bb_, ldb_, Kdim_)                                           \
    __shared__ __align__(16) ushort_t lds[2][2][2][128 * 64];                               \
    const int tid  = threadIdx.x;                                                           \
    const int lane = tid & 63;                                                              \
    const int wave = tid >> 6;                                                              \
    const int wm = wave >> 2, wn = wave & 3;                                                \
    const int r16 = lane & 15, kb = lane >> 4;                                              \
    f32x4 acc[8][4];                                                                        \
    _Pragma("unroll") for (int i = 0; i < 8; ++i)                                           \
        _Pragma("unroll") for (int j = 0; j < 4; ++j)                                       \
            acc[i][j] = (f32x4){0.f, 0.f, 0.f, 0.f};                                        \
    auto stage = [&](int kt) {                                                              \
        const int d  = kt & 1;                                                              \
        const int k0 = kt * 64;                                                             \
        _Pragma("unroll") for (int arr = 0; arr < 2; ++arr)                                 \
        _Pragma("unroll") for (int h = 0; h < 2; ++h)                                       \
        _Pragma("unroll") for (int l = 0; l < 2; ++l) {                                     \
            const int idx = l * 512 + tid;                                                  \
            const int row = idx >> 3, sl = idx & 7;                                         \
            const int ssrc = sl ^ (row & 7);                                                \
            const long long grow = h * 128 + row;                                           \
            const ushort_t* g = (arr == 0)                                                  \
                ? (Ab_) + (tM + grow) * (long long)(lda_) + k0 + ssrc * 8                   \
                : (Bb_) + (tN + grow) * (long long)(ldb_) + k0 + ssrc * 8;                  \
            ushort_t* lp = &lds[d][arr][h][idx * 8];                                        \
            __builtin_amdgcn_global_load_lds((const __attribute__((address_space(1))) void*)g, \
                                             (__attribute__((address_space(3))) void*)lp, 16, 0, 0); \
        }                                                                                   \
    };                                                                                      \
    auto compute = [&](int kt) {                                                            \
        const int d = kt & 1;                                                               \
        _Pragma("unroll") for (int kk = 0; kk < 2; ++kk) {                                  \
            bf16x8 bfr[4];                                                                  \
            _Pragma("unroll") for (int ni = 0; ni < 4; ++ni) {                              \
                const int row = (wn & 1) * 64 + ni * 16 + r16;                              \
                const int o16 = row * 8 + ((kk * 4 + kb) ^ (row & 7));                      \
                bfr[ni] = *(const bf16x8*)((const char*)&lds[d][1][wn >> 1][0] + o16 * 16); \
            }                                                                               \
            __builtin_amdgcn_s_setprio(1);                                                  \
            _Pragma("unroll") for (int mi = 0; mi < 8; ++mi) {                              \
                const int row = mi * 16 + r16;                                              \
                const int o16 = row * 8 + ((kk * 4 + kb) ^ (row & 7));                      \
                bf16x8 af = *(const bf16x8*)((const char*)&lds[d][0][wm][0] + o16 * 16);    \
                _Pragma("unroll") for (int ni = 0; ni < 4; ++ni)                            \
                    acc[mi][ni] = __builtin_amdgcn_mfma_f32_16x16x32_bf16(af, bfr[ni], acc[mi][ni], 0, 0, 0); \
            }                                                                               \
            __builtin_amdgcn_s_setprio(0);                                                  \
        }                                                                                   \
    };                                                                                      \
    const int NT = (Kdim_) / 64;                                                            \
    stage(0);                                                                               \
    __syncthreads();                                                                        \
    for (int t = 0; t < NT; ++t) {                                                          \
        if (t + 1 < NT) stage(t + 1);                                                       \
        compute(t);                                                                         \
        __syncthreads();                                                                    \
    }                                                                                       \
    const int rquad = (lane >> 4) * 4;                                                      \
    const int cl    = lane & 15;

// ============================================================================
// 128x128 / BK=64 / 256-thread 2-PHASE core (pvn-proven: 64KB LDS, 2/CU).
// Only wins when K is LONG (pvn K=2048) — r16 lesson.
// ============================================================================
#define GEMM128_CORE(Ab_, lda_, Bb_, ldb_, NTv)                                             \
    __shared__ __align__(16) ushort_t lds[2][2][128 * 64];                                  \
    const int tid  = threadIdx.x;                                                           \
    const int lane = tid & 63;                                                              \
    const int wave = tid >> 6;                                                              \
    const int wr = wave >> 1, wc = wave & 1;                                                \
    f32x4 acc[4][4];                                                                        \
    _Pragma("unroll") for (int i = 0; i < 4; ++i)                                           \
        _Pragma("unroll") for (int j = 0; j < 4; ++j)                                       \
            acc[i][j] = (f32x4){0.f, 0.f, 0.f, 0.f};                                        \
    auto stage = [&](int buf, int kt) {                                                     \
        const int k0 = kt * 64;                                                             \
        _Pragma("unroll") for (int rnd = 0; rnd < 4; ++rnd) {                               \
            const int idx  = rnd * 256 + tid;                                               \
            const int row  = idx >> 3;                                                      \
            const int slot = idx & 7;                                                       \
            const int ssrc = slot ^ (row & 7);                                              \
            const ushort_t* ga = (Ab_) + (tM + row) * (long long)(lda_) + k0 + ssrc * 8;    \
            const ushort_t* gb = (Bb_) + (tN + row) * (long long)(ldb_) + k0 + ssrc * 8;    \
            __builtin_amdgcn_global_load_lds((const __attribute__((address_space(1))) void*)ga, \
                (__attribute__((address_space(3))) void*)&lds[buf][0][idx * 8], 16, 0, 0);  \
            __builtin_amdgcn_global_load_lds((const __attribute__((address_space(1))) void*)gb, \
                (__attribute__((address_space(3))) void*)&lds[buf][1][idx * 8], 16, 0, 0);  \
        }                                                                                   \
    };                                                                                      \
    auto compute = [&](int buf) {                                                           \
        const int kbb = lane >> 4;                                                          \
        const int r16 = lane & 15;                                                          \
        _Pragma("unroll") for (int kk = 0; kk < 2; ++kk) {                                  \
            bf16x8 af[4], bfr[4];                                                           \
            _Pragma("unroll") for (int mi = 0; mi < 4; ++mi) {                              \
                const int row = wr * 64 + mi * 16 + r16;                                    \
                const int o16 = row * 8 + ((kk * 4 + kbb) ^ (row & 7));                     \
                af[mi] = *(const bf16x8*)((const char*)lds[buf][0] + o16 * 16);             \
            }                                                                               \
            _Pragma("unroll") for (int ni = 0; ni < 4; ++ni) {                              \
                const int row = wc * 64 + ni * 16 + r16;                                    \
                const int o16 = row * 8 + ((kk * 4 + kbb) ^ (row & 7));                     \
                bfr[ni] = *(const bf16x8*)((const char*)lds[buf][1] + o16 * 16);            \
            }                                                                               \
            __builtin_amdgcn_s_setprio(1);                                                  \
            _Pragma("unroll") for (int mi = 0; mi < 4; ++mi)                                \
                _Pragma("unroll") for (int ni = 0; ni < 4; ++ni)                            \
                    acc[mi][ni] = __builtin_amdgcn_mfma_f32_16x16x32_bf16(af[mi], bfr[ni], acc[mi][ni], 0, 0, 0); \
            __builtin_amdgcn_s_setprio(0);                                                  \
        }                                                                                   \
    };                                                                                      \
    stage(0, 0);                                                                            \
    __syncthreads();                                                                        \
    int cur = 0;                                                                            \
    for (int kt = 0; kt + 1 < (NTv); ++kt) {                                                \
        stage(cur ^ 1, kt + 1);                                                             \
        compute(cur);                                                                       \
        __syncthreads();                                                                    \
        cur ^= 1;                                                                           \
    }                                                                                       \
    compute(cur);                                                                           \
    const int rquad = (lane >> 4) * 4;                                                      \
    const int cl    = lane & 15;

// ------ fused: V-projection (blocks 0..95, 256^2 core) + cvt q,k (96..255) --
__global__ __launch_bounds__(512, 2)
void vprojcvt(const ushort_t* __restrict__ wv_, const ushort_t* __restrict__ vb_,
              const float* __restrict__ bv_, ushort_t* __restrict__ dvT_,
              const float* __restrict__ qf_, const float* __restrict__ kf_,
              ushort_t* __restrict__ qb_, ushort_t* __restrict__ kb_)
{
    if (blockIdx.x < 96) {
        const int id = blockIdx.x;
        const long long tM = (long long)(id % 3) * 256;    // feature rows (768)
        const long long tN = (long long)(id / 3) * 256;    // token cols (8192)
        const ushort_t* Ab = wv_;
        const ushort_t* Bb = vb_;

        GEMM256_CORE(Ab, 768, Bb, 768, 768)

#pragma unroll
        for (int mi = 0; mi < 8; ++mi) {
            const long long r = tM + wm * 128 + mi * 16 + rquad;
#pragma unroll
            for (int ni = 0; ni < 4; ++ni) {
                f32x4 v = acc[mi][ni];
                const long long c = tN + wn * 64 + ni * 16 + cl;
#pragma unroll
                for (int j = 0; j < 4; ++j)
                    dvT_[(r + j) * 8192 + c] = f2bf(v[j] + bv_[r + j]);
            }
        }
    } else {
        const long long stride = 160LL * 512;
        for (long long i = (long long)(blockIdx.x - 96) * 512 + threadIdx.x;
             i < 2LL * 1572864; i += stride) {
            const float* src; ushort_t* dst; long long off;
            if (i < 1572864) { src = qf_; dst = qb_; off = i; }
            else             { src = kf_; dst = kb_; off = i - 1572864; }
            f32x4v v4 = ((const f32x4v*)src)[off];
            u16x4 o = { f2bf(v4.x), f2bf(v4.y), f2bf(v4.z), f2bf(v4.w) };
            ((u16x4*)dst)[off] = o;
        }
    }
}

// ---------------- Q,K projections: grid (3,32,2) = 192 blocks, 1 round ------
__global__ __launch_bounds__(512, 2)
void projqk2(const ushort_t* __restrict__ qin, const ushort_t* __restrict__ kin,
             const ushort_t* __restrict__ Wqb, const ushort_t* __restrict__ Wkb,
             const float* __restrict__ bqv, const float* __restrict__ bkv,
             ushort_t* __restrict__ dq, ushort_t* __restrict__ dk)
{
    int bx, by, bz;
    xcd_remap(bx, by, bz);
    const int z = bz;
    const long long tM = (long long)by * 256;
    const long long tN = (long long)bx * 256;
    const ushort_t* Ab = z ? kin : qin;
    const ushort_t* Bb = z ? Wkb : Wqb;
    const float* bias  = z ? bkv : bqv;
    ushort_t* dst      = z ? dk : dq;

    GEMM256_CORE(Ab, 768, Bb, 768, 768)

#pragma unroll
    for (int mi = 0; mi < 8; ++mi) {
        const long long r = tM + wm * 128 + mi * 16 + rquad;
#pragma unroll
        for (int ni = 0; ni < 4; ++ni) {
            f32x4 v = acc[mi][ni];
            const long long c = tN + wn * 64 + ni * 16 + cl;
            const float bc = bias[c];
#pragma unroll
            for (int j = 0; j < 4; ++j)
                dst[(r + j) * 768 + c] = f2bf(v[j] + bc);
        }
    }
}

// ============================================================================
// sexp: P~ = exp(scale * qp@kp^T) bf16. 256x128 tile / BK=32 / 256 threads.
// Grid (16,8,4) = 512 blocks = ONE round at 2 blocks/CU; 24 K-steps/block
// (2x the warm-up amortization of the 128^2/BK64 form, no 2nd-round restart).
// LDS 48KB: A[256][32] + B[128][32] dbuf. 4-slot swizzle slot^(row&3).
// Waves 2x2; per-wave 128x64 output: acc[8][4] (128 AGPRs).
// ============================================================================
__global__ __launch_bounds__(256, 2)
void sexp256x128(const ushort_t* __restrict__ qp, const ushort_t* __restrict__ kp,
                 ushort_t* __restrict__ P, float scale)
{
    int bx, by, bz;
    xcd_remap(bx, by, bz);   // grid (16,8,4): bx = N-tile, by = M-tile, bz = batch
    const long long tM = (long long)by * 256;
    const long long tN = (long long)bx * 128;
    const int z = bz;
    const ushort_t* Ab = qp + (long long)z * 1572864;
    const ushort_t* Bb = kp + (long long)z * 1572864;

    __shared__ __align__(16) ushort_t lds[2][(256 + 128) * 32];   // 48 KB total
    const int tid  = threadIdx.x;
    const int lane = tid & 63;
    const int wave = tid >> 6;
    const int wm = wave >> 1, wn = wave & 1;   // 2 (M) x 2 (N) waves

    f32x4 acc[8][4];
#pragma unroll
    for (int i = 0; i < 8; ++i)
#pragma unroll
        for (int j = 0; j < 4; ++j)
            acc[i][j] = (f32x4){0.f, 0.f, 0.f, 0.f};

    auto stage = [&](int buf, int kt) {
        const int k0 = kt * 32;
        // A: 256 rows x 4 slots = 1024 16B loads
#pragma unroll
        for (int rnd = 0; rnd < 4; ++rnd) {
            const int idx  = rnd * 256 + tid;       // 0..1023
            const int row  = idx >> 2;
            const int slot = idx & 3;
            const int ssrc = slot ^ (row & 3);
            const ushort_t* ga = Ab + (tM + row) * 768LL + k0 + ssrc * 8;
            __builtin_amdgcn_global_load_lds((const __attribute__((address_space(1))) void*)ga,
                                             (__attribute__((address_space(3))) void*)&lds[buf][idx * 8], 16, 0, 0);
        }
        // B: 128 rows x 4 slots = 512 16B loads
#pragma unroll
        for (int rnd = 0; rnd < 2; ++rnd) {
            const int idx  = rnd * 256 + tid;       // 0..511
            const int row  = idx >> 2;
            const int slot = idx & 3;
            const int ssrc = slot ^ (row & 3);
            const ushort_t* gb = Bb + (tN + row) * 768LL + k0 + ssrc * 8;
            __builtin_amdgcn_global_load_lds((const __attribute__((address_space(1))) void*)gb,
                                             (__attribute__((address_space(3))) void*)&lds[buf][8192 + idx * 8], 16, 0, 0);
        }
    };
    auto compute = [&](int buf) {
        const int kbb = lane >> 4;      // 0..3: which 16B slot along K=32
        const int r16 = lane & 15;
        bf16x8 bfr[4];
#pragma unroll
        for (int ni = 0; ni < 4; ++ni) {
            const int row = wn * 64 + ni * 16 + r16;
            const int o16 = row * 4 + (kbb ^ (row & 3));
            bfr[ni] = *(const bf16x8*)((const char*)&lds[buf][8192] + o16 * 16);
        }
        __builtin_amdgcn_s_setprio(1);
#pragma unroll
        for (int mi = 0; mi < 8; ++mi) {
            const int row = wm * 128 + mi * 16 + r16;
            const int o16 = row * 4 + (kbb ^ (row & 3));
            bf16x8 af = *(const bf16x8*)((const char*)&lds[buf][0] + o16 * 16);
#pragma unroll
            for (int ni = 0; ni < 4; ++ni)
                acc[mi][ni] = __builtin_amdgcn_mfma_f32_16x16x32_bf16(af, bfr[ni], acc[mi][ni], 0, 0, 0);
        }
        __builtin_amdgcn_s_setprio(0);
    };

    stage(0, 0);
    __syncthreads();
    int cur = 0;
    for (int kt = 0; kt + 1 < 24; ++kt) {
        stage(cur ^ 1, kt + 1);
        compute(cur);
        __syncthreads();
        cur ^= 1;
    }
    compute(cur);

    const int rquad = (lane >> 4) * 4;
    const int cl    = lane & 15;
    ushort_t* out = P + (long long)z * 4194304;
#pragma unroll
    for (int mi = 0; mi < 8; ++mi) {
        const long long r = tM + wm * 128 + mi * 16 + rquad;
#pragma unroll
        for (int ni = 0; ni < 4; ++ni) {
            f32x4 v = acc[mi][ni];
            const long long c = tN + wn * 64 + ni * 16 + cl;
#pragma unroll
            for (int j = 0; j < 4; ++j)
                out[(r + j) * 2048 + c] = f2bf(__expf(v[j] * scale));
        }
    }
}

// ============================================================================
// PVN: O = (P @ Vp^T) / rowsum. 128x128 / BK=64 core, rowsum via ones-MFMA.
// ============================================================================
__global__ __launch_bounds__(256, 2)
void pvn_rs(const ushort_t* __restrict__ Pg, const ushort_t* __restrict__ vpT,
            ushort_t* __restrict__ Og)
{
    int bx, by, bz;
    xcd_remap(bx, by, bz);
    const long long tM = (long long)by * 128;
    const long long tN = (long long)bx * 128;
    const int z = bz;
    const ushort_t* Ab = Pg + (long long)z * 4194304;   // P: [2048][2048] bf16
    const ushort_t* Bb = vpT + (long long)z * 2048;     // vpT: [768][8192], batch = col offset

    __shared__ __align__(16) ushort_t lds[2][2][128 * 64];   // 64 KB
    const int tid  = threadIdx.x;
    const int lane = tid & 63;
    const int wave = tid >> 6;
    const int wr = wave >> 1, wc = wave & 1;

    const u16x8 oneb = {0x3F80,0x3F80,0x3F80,0x3F80,0x3F80,0x3F80,0x3F80,0x3F80};
    const bf16x8 ones = __builtin_bit_cast(bf16x8, oneb);

    f32x4 acc[4][4];
    f32x4 rs4[4];
#pragma unroll
    for (int i = 0; i < 4; ++i) {
        rs4[i] = (f32x4){0.f, 0.f, 0.f, 0.f};
#pragma unroll
        for (int j = 0; j < 4; ++j)
            acc[i][j] = (f32x4){0.f, 0.f, 0.f, 0.f};
    }

    auto stage = [&](int buf, int kt) {
        const int k0 = kt * 64;
#pragma unroll
        for (int rnd = 0; rnd < 4; ++rnd) {
            const int idx  = rnd * 256 + tid;
            const int row  = idx >> 3;
            const int slot = idx & 7;
            const int ssrc = slot ^ (row & 7);
            const ushort_t* ga = Ab + (tM + row) * 2048LL + k0 + ssrc * 8;
            const ushort_t* gb = Bb + (tN + row) * 8192LL + k0 + ssrc * 8;
            __builtin_amdgcn_global_load_lds((const __attribute__((address_space(1))) void*)ga,
                                             (__attribute__((address_space(3))) void*)&lds[buf][0][idx * 8], 16, 0, 0);
            __builtin_amdgcn_global_load_lds((const __attribute__((address_space(1))) void*)gb,
                                             (__attribute__((address_space(3))) void*)&lds[buf][1][idx * 8], 16, 0, 0);
        }
    };
    auto compute = [&](int buf) {
        const int kbb = lane >> 4;
        const int r16 = lane & 15;
#pragma unroll
        for (int kk = 0; kk < 2; ++kk) {
            bf16x8 af[4], bfr[4];
#pragma unroll
            for (int mi = 0; mi < 4; ++mi) {
                const int row = wr * 64 + mi * 16 + r16;
                const int o16 = row * 8 + ((kk * 4 + kbb) ^ (row & 7));
                af[mi] = *(const bf16x8*)((const char*)lds[buf][0] + o16 * 16);
            }
#pragma unroll
            for (int ni = 0; ni < 4; ++ni) {
                const int row = wc * 64 + ni * 16 + r16;
                const int o16 = row * 8 + ((kk * 4 + kbb) ^ (row & 7));
                bfr[ni] = *(const bf16x8*)((const char*)lds[buf][1] + o16 * 16);
            }
            __builtin_amdgcn_s_setprio(1);
#pragma unroll
            for (int mi = 0; mi < 4; ++mi) {
#pragma unroll
                for (int ni = 0; ni < 4; ++ni)
                    acc[mi][ni] = __builtin_amdgcn_mfma_f32_16x16x32_bf16(af[mi], bfr[ni], acc[mi][ni], 0, 0, 0);
                rs4[mi] = __builtin_amdgcn_mfma_f32_16x16x32_bf16(af[mi], ones, rs4[mi], 0, 0, 0);
            }
            __builtin_amdgcn_s_setprio(0);
        }
    };

    stage(0, 0);
    __syncthreads();
    int cur = 0;
    for (int kt = 0; kt + 1 < 32; ++kt) {
        stage(cur ^ 1, kt + 1);
        compute(cur);
        __syncthreads();
        cur ^= 1;
    }
    compute(cur);

    const int rquad = (lane >> 4) * 4;
    const int cl    = lane & 15;
    ushort_t* out = Og + (long long)z * 1572864;
#pragma unroll
    for (int mi = 0; mi < 4; ++mi) {
        const long long r = tM + wr * 64 + mi * 16 + rquad;
        float inv[4];
#pragma unroll
        for (int j = 0; j < 4; ++j)
            inv[j] = 1.0f / rs4[mi][j];
#pragma unroll
        for (int ni = 0; ni < 4; ++ni) {
            f32x4 v = acc[mi][ni];
            const long long c = tN + wc * 64 + ni * 16 + cl;
#pragma unroll
            for (int j = 0; j < 4; ++j)
                out[(r + j) * 768 + c] = f2bf(v[j] * inv[j]);
        }
    }
}

// ---------------- OUT: fp32 = O @ Wp^T + bp, 128x128 / BK=64 core -----------
__global__ __launch_bounds__(256, 2)
void gemm_out(const ushort_t* __restrict__ A, const ushort_t* __restrict__ B,
              float* __restrict__ Cg, const float* __restrict__ bias)
{
    int bx, by, bz;
    xcd_remap(bx, by, bz);
    const long long tM = (long long)by * 128;
    const long long tN = (long long)bx * 128;
    const ushort_t* Ab = A;
    const ushort_t* Bb = B;

    GEMM128_CORE(Ab, 768, Bb, 768, 12)

#pragma unroll
    for (int mi = 0; mi < 4; ++mi) {
        const long long r = tM + wr * 64 + mi * 16 + rquad;
#pragma unroll
        for (int ni = 0; ni < 4; ++ni) {
            f32x4 v = acc[mi][ni];
            const long long c = tN + wc * 64 + ni * 16 + cl;
            const float bc = bias[c];
#pragma unroll
            for (int j = 0; j < 4; ++j)
                Cg[(r + j) * 768 + c] = v[j] + bc;
        }
    }
}

// ---------------- launch ----------------
extern "C" void kernel_launch(void* const* d_in, const int* in_sizes, int n_in,
                              void* d_out, int out_size, void* d_ws, size_t ws_size,
                              hipStream_t stream) {
    (void)in_sizes; (void)n_in; (void)out_size; (void)ws_size;
    const float* q  = (const float*)d_in[0];
    const float* k  = (const float*)d_in[1];
    const float* v  = (const float*)d_in[2];
    const float* Wq = (const float*)d_in[3];
    const float* bq = (const float*)d_in[4];
    const float* Wk = (const float*)d_in[5];
    const float* bk = (const float*)d_in[6];
    const float* Wv = (const float*)d_in[7];
    const float* bv = (const float*)d_in[8];
    const float* Wp = (const float*)d_in[9];
    const float* bp = (const float*)d_in[10];
    float* out = (float*)d_out;

    // ---- workspace layout (round-9 proven, no live-overlay) ----
    char* ws = (char*)d_ws;
    ushort_t* vb  = (ushort_t*)(ws);                 // [0, 12.6M)
    ushort_t* qb  = (ushort_t*)(ws + 12582912LL);
    ushort_t* kb  = (ushort_t*)(ws + 25165824LL);
    ushort_t* P   = (ushort_t*)(ws + 12582912LL);    // overlays dead qb,kb + gap
    ushort_t* Wqb = (ushort_t*)(ws + 46137344LL);
    ushort_t* Wkb = (ushort_t*)(ws + 47316992LL);
    ushort_t* Wvb = (ushort_t*)(ws + 48496640LL);
    ushort_t* Wpb = (ushort_t*)(ws + 49676288LL);
    ushort_t* qp  = (ushort_t*)(ws + 50855936LL);    // [8192][768] bf16
    ushort_t* kp  = (ushort_t*)(ws + 63438848LL);    // [8192][768] bf16
    ushort_t* vpT = (ushort_t*)(ws + 76021760LL);    // [768][8192] bf16
    ushort_t* Ob  = qp;                              // O overlays dead qp

    const float scale = 1.0f / sqrtf(768.0f);

    // 1) merged prep: cvt v + 4 weights
    cvt_all<<<8448, 256, 0, stream>>>(v, Wq, Wk, Wv, Wp, vb, Wqb, Wkb, Wvb, Wpb);

    // 2) fused: V-projection (96 tiles, 256^2 core) + cvt q,k (160 blocks)
    vprojcvt<<<256, 512, 0, stream>>>(Wvb, vb, bv, vpT, q, k, qb, kb);

    // 3) Q,K projections (192 tiles, 1 round)
    projqk2<<<dim3(3, 32, 2), 512, 0, stream>>>(qb, kb, Wqb, Wkb, bq, bk, qp, kp);

    // 4) P~ = exp(scale * QK^T)  (256x128/BK=32 tiles, 512 blocks, ONE round)
    sexp256x128<<<dim3(16, 8, 4), 256, 0, stream>>>(qp, kp, P, scale);

    // 5) O = (P~ @ Vp^T) / rowsum   (rowsum via ones-MFMA; BK=64, 32 K-steps)
    pvn_rs<<<dim3(6, 16, 4), 256, 0, stream>>>(P, vpT, Ob);

    // 6) out = O @ Wp^T + bp  (BK=64, 12 K-steps)
    gemm_out<<<dim3(6, 64, 1), 256, 0, stream>>>(Ob, Wpb, out, bp);
}

// Round 19
// 147.031 us; speedup vs baseline: 1.0167x; 1.0167x over previous
//
#include <hip/hip_runtime.h>
#include <hip/hip_bf16.h>
#include <math.h>

typedef __bf16 bf16x8 __attribute__((ext_vector_type(8)));
typedef float  f32x4  __attribute__((ext_vector_type(4)));
typedef float  f32x4v __attribute__((ext_vector_type(4)));
typedef unsigned short ushort_t;
typedef ushort_t u16x4 __attribute__((ext_vector_type(4)));
typedef ushort_t u16x8 __attribute__((ext_vector_type(8)));

__device__ __forceinline__ ushort_t f2bf(float f) {
    unsigned u = __builtin_bit_cast(unsigned, f);
    u += 0x7FFFu + ((u >> 16) & 1u);
    return (ushort_t)(u >> 16);
}

// XCD-aware bijective remap (m157/m204). Requires total grid % 8 == 0.
__device__ __forceinline__ void xcd_remap(int& bx, int& by, int& bz) {
    const int gx = gridDim.x, gy = gridDim.y;
    const int nwg = gx * gy * gridDim.z;
    const int lin = (blockIdx.z * gy + blockIdx.y) * gx + blockIdx.x;
    const int chunk = nwg >> 3;
    int nid = (lin & 7) * chunk + (lin >> 3);
    bx = nid % gx; nid /= gx;
    by = nid % gy; bz = nid / gy;
}

// ---- merged prep launch: cvt v (6144 blocks) + 4 weights (4x576) ----
__global__ __launch_bounds__(256)
void cvt_all(const float* __restrict__ v, const float* __restrict__ Wq,
             const float* __restrict__ Wk, const float* __restrict__ Wv,
             const float* __restrict__ Wp,
             ushort_t* __restrict__ vb, ushort_t* __restrict__ Wqb,
             ushort_t* __restrict__ Wkb, ushort_t* __restrict__ Wvb,
             ushort_t* __restrict__ Wpb)
{
    const int b = blockIdx.x;
    if (b < 6144) {
        int i = b * 256 + threadIdx.x;
        f32x4v x = ((const f32x4v*)v)[i];
        u16x4 o = { f2bf(x.x), f2bf(x.y), f2bf(x.z), f2bf(x.w) };
        ((u16x4*)vb)[i] = o;
    } else {
        const int w = (b - 6144) / 576;
        const int bb = (b - 6144) % 576;
        const float* in  = w == 0 ? Wq : w == 1 ? Wk : w == 2 ? Wv : Wp;
        ushort_t*    out = w == 0 ? Wqb : w == 1 ? Wkb : w == 2 ? Wvb : Wpb;
        int i = bb * 256 + threadIdx.x;
        f32x4v x = ((const f32x4v*)in)[i];
        u16x4 o = { f2bf(x.x), f2bf(x.y), f2bf(x.z), f2bf(x.w) };
        ((u16x4*)out)[i] = o;
    }
}

// ============================================================================
// 256x256 / BK=64 / 8-wave 2-PHASE core (round-6 proven). T2 swizzle applied
// inverse-on-source (linear gload_lds dest, rule #21), T5 setprio.
// ============================================================================
#define GEMM256_CORE(Ab_, lda_, Bb_, ldb_, Kdim_)                                           \
    __shared__ __align__(16) ushort_t lds[2][2][2][128 * 64];                               \
    const int tid  = threadIdx.x;                                                           \
    const int lane = tid & 63;                                                              \
    const int wave = tid >> 6;                                                              \
    const int wm = wave >> 2, wn = wave & 3;                                                \
    const int r16 = lane & 15, kb = lane >> 4;                                              \
    f32x4 acc[8][4];                                                                        \
    _Pragma("unroll") for (int i = 0; i < 8; ++i)                                           \
        _Pragma("unroll") for (int j = 0; j < 4; ++j)                                       \
            acc[i][j] = (f32x4){0.f, 0.f, 0.f, 0.f};                                        \
    auto stage = [&](int kt) {                                                              \
        const int d  = kt & 1;                                                              \
        const int k0 = kt * 64;                                                             \
        _Pragma("unroll") for (int arr = 0; arr < 2; ++arr)                                 \
        _Pragma("unroll") for (int h = 0; h < 2; ++h)                                       \
        _Pragma("unroll") for (int l = 0; l < 2; ++l) {                                     \
            const int idx = l * 512 + tid;                                                  \
            const int row = idx >> 3, sl = idx & 7;                                         \
            const int ssrc = sl ^ (row & 7);                                                \
            const long long grow = h * 128 + row;                                           \
            const ushort_t* g = (arr == 0)                                                  \
                ? (Ab_) + (tM + grow) * (long long)(lda_) + k0 + ssrc * 8                   \
                : (Bb_) + (tN + grow) * (long long)(ldb_) + k0 + ssrc * 8;                  \
            ushort_t* lp = &lds[d][arr][h][idx * 8];                                        \
            __builtin_amdgcn_global_load_lds((const __attribute__((address_space(1))) void*)g, \
                                             (__attribute__((address_space(3))) void*)lp, 16, 0, 0); \
        }                                                                                   \
    };                                                                                      \
    auto compute = [&](int kt) {                                                            \
        const int d = kt & 1;                                                               \
        _Pragma("unroll") for (int kk = 0; kk < 2; ++kk) {                                  \
            bf16x8 bfr[4];                                                                  \
            _Pragma("unroll") for (int ni = 0; ni < 4; ++ni) {                              \
                const int row = (wn & 1) * 64 + ni * 16 + r16;                              \
                const int o16 = row * 8 + ((kk * 4 + kb) ^ (row & 7));                      \
                bfr[ni] = *(const bf16x8*)((const char*)&lds[d][1][wn >> 1][0] + o16 * 16); \
            }                                                                               \
            __builtin_amdgcn_s_setprio(1);                                                  \
            _Pragma("unroll") for (int mi = 0; mi < 8; ++mi) {                              \
                const int row = mi * 16 + r16;                                              \
                const int o16 = row * 8 + ((kk * 4 + kb) ^ (row & 7));                      \
                bf16x8 af = *(const bf16x8*)((const char*)&lds[d][0][wm][0] + o16 * 16);    \
                _Pragma("unroll") for (int ni = 0; ni < 4; ++ni)                            \
                    acc[mi][ni] = __builtin_amdgcn_mfma_f32_16x16x32_bf16(af, bfr[ni], acc[mi][ni], 0, 0, 0); \
            }                                                                               \
            __builtin_amdgcn_s_setprio(0);                                                  \
        }                                                                                   \
    };                                                                                      \
    const int NT = (Kdim_) / 64;                                                            \
    stage(0);                                                                               \
    __syncthreads();                                                                        \
    for (int t = 0; t < NT; ++t) {                                                          \
        if (t + 1 < NT) stage(t + 1);                                                       \
        compute(t);                                                                         \
        __syncthreads();                                                                    \
    }                                                                                       \
    const int rquad = (lane >> 4) * 4;                                                      \
    const int cl    = lane & 15;

// ============================================================================
// 128x128 / BK=64 / 256-thread 2-PHASE core (pvn-proven: 64KB LDS, 2/CU).
// Only wins when K is LONG (pvn K=2048) — r16 lesson.
// ============================================================================
#define GEMM128_CORE(Ab_, lda_, Bb_, ldb_, NTv)                                             \
    __shared__ __align__(16) ushort_t lds[2][2][128 * 64];                                  \
    const int tid  = threadIdx.x;                                                           \
    const int lane = tid & 63;                                                              \
    const int wave = tid >> 6;                                                              \
    const int wr = wave >> 1, wc = wave & 1;                                                \
    f32x4 acc[4][4];                                                                        \
    _Pragma("unroll") for (int i = 0; i < 4; ++i)                                           \
        _Pragma("unroll") for (int j = 0; j < 4; ++j)                                       \
            acc[i][j] = (f32x4){0.f, 0.f, 0.f, 0.f};                                        \
    auto stage = [&](int buf, int kt) {                                                     \
        const int k0 = kt * 64;                                                             \
        _Pragma("unroll") for (int rnd = 0; rnd < 4; ++rnd) {                               \
            const int idx  = rnd * 256 + tid;                                               \
            const int row  = idx >> 3;                                                      \
            const int slot = idx & 7;                                                       \
            const int ssrc = slot ^ (row & 7);                                              \
            const ushort_t* ga = (Ab_) + (tM + row) * (long long)(lda_) + k0 + ssrc * 8;    \
            const ushort_t* gb = (Bb_) + (tN + row) * (long long)(ldb_) + k0 + ssrc * 8;    \
            __builtin_amdgcn_global_load_lds((const __attribute__((address_space(1))) void*)ga, \
                (__attribute__((address_space(3))) void*)&lds[buf][0][idx * 8], 16, 0, 0);  \
            __builtin_amdgcn_global_load_lds((const __attribute__((address_space(1))) void*)gb, \
                (__attribute__((address_space(3))) void*)&lds[buf][1][idx * 8], 16, 0, 0);  \
        }                                                                                   \
    };                                                                                      \
    auto compute = [&](int buf) {                                                           \
        const int kbb = lane >> 4;                                                          \
        const int r16 = lane & 15;                                                          \
        _Pragma("unroll") for (int kk = 0; kk < 2; ++kk) {                                  \
            bf16x8 af[4], bfr[4];                                                           \
            _Pragma("unroll") for (int mi = 0; mi < 4; ++mi) {                              \
                const int row = wr * 64 + mi * 16 + r16;                                    \
                const int o16 = row * 8 + ((kk * 4 + kbb) ^ (row & 7));                     \
                af[mi] = *(const bf16x8*)((const char*)lds[buf][0] + o16 * 16);             \
            }                                                                               \
            _Pragma("unroll") for (int ni = 0; ni < 4; ++ni) {                              \
                const int row = wc * 64 + ni * 16 + r16;                                    \
                const int o16 = row * 8 + ((kk * 4 + kbb) ^ (row & 7));                     \
                bfr[ni] = *(const bf16x8*)((const char*)lds[buf][1] + o16 * 16);            \
            }                                                                               \
            __builtin_amdgcn_s_setprio(1);                                                  \
            _Pragma("unroll") for (int mi = 0; mi < 4; ++mi)                                \
                _Pragma("unroll") for (int ni = 0; ni < 4; ++ni)                            \
                    acc[mi][ni] = __builtin_amdgcn_mfma_f32_16x16x32_bf16(af[mi], bfr[ni], acc[mi][ni], 0, 0, 0); \
            __builtin_amdgcn_s_setprio(0);                                                  \
        }                                                                                   \
    };                                                                                      \
    stage(0, 0);                                                                            \
    __syncthreads();                                                                        \
    int cur = 0;                                                                            \
    for (int kt = 0; kt + 1 < (NTv); ++kt) {                                                \
        stage(cur ^ 1, kt + 1);                                                             \
        compute(cur);                                                                       \
        __syncthreads();                                                                    \
        cur ^= 1;                                                                           \
    }                                                                                       \
    compute(cur);                                                                           \
    const int rquad = (lane >> 4) * 4;                                                      \
    const int cl    = lane & 15;

// ------ fused: V-projection (blocks 0..95, 256^2 core) + cvt q,k (96..255) --
__global__ __launch_bounds__(512, 2)
void vprojcvt(const ushort_t* __restrict__ wv_, const ushort_t* __restrict__ vb_,
              const float* __restrict__ bv_, ushort_t* __restrict__ dvT_,
              const float* __restrict__ qf_, const float* __restrict__ kf_,
              ushort_t* __restrict__ qb_, ushort_t* __restrict__ kb_)
{
    if (blockIdx.x < 96) {
        const int id = blockIdx.x;
        const long long tM = (long long)(id % 3) * 256;    // feature rows (768)
        const long long tN = (long long)(id / 3) * 256;    // token cols (8192)
        const ushort_t* Ab = wv_;
        const ushort_t* Bb = vb_;

        GEMM256_CORE(Ab, 768, Bb, 768, 768)

#pragma unroll
        for (int mi = 0; mi < 8; ++mi) {
            const long long r = tM + wm * 128 + mi * 16 + rquad;
#pragma unroll
            for (int ni = 0; ni < 4; ++ni) {
                f32x4 v = acc[mi][ni];
                const long long c = tN + wn * 64 + ni * 16 + cl;
#pragma unroll
                for (int j = 0; j < 4; ++j)
                    dvT_[(r + j) * 8192 + c] = f2bf(v[j] + bv_[r + j]);
            }
        }
    } else {
        const long long stride = 160LL * 512;
        for (long long i = (long long)(blockIdx.x - 96) * 512 + threadIdx.x;
             i < 2LL * 1572864; i += stride) {
            const float* src; ushort_t* dst; long long off;
            if (i < 1572864) { src = qf_; dst = qb_; off = i; }
            else             { src = kf_; dst = kb_; off = i - 1572864; }
            f32x4v v4 = ((const f32x4v*)src)[off];
            u16x4 o = { f2bf(v4.x), f2bf(v4.y), f2bf(v4.z), f2bf(v4.w) };
            ((u16x4*)dst)[off] = o;
        }
    }
}

// ---------------- Q,K projections: grid (3,32,2) = 192 blocks, 1 round ------
__global__ __launch_bounds__(512, 2)
void projqk2(const ushort_t* __restrict__ qin, const ushort_t* __restrict__ kin,
             const ushort_t* __restrict__ Wqb, const ushort_t* __restrict__ Wkb,
             const float* __restrict__ bqv, const float* __restrict__ bkv,
             ushort_t* __restrict__ dq, ushort_t* __restrict__ dk)
{
    int bx, by, bz;
    xcd_remap(bx, by, bz);
    const int z = bz;
    const long long tM = (long long)by * 256;
    const long long tN = (long long)bx * 256;
    const ushort_t* Ab = z ? kin : qin;
    const ushort_t* Bb = z ? Wkb : Wqb;
    const float* bias  = z ? bkv : bqv;
    ushort_t* dst      = z ? dk : dq;

    GEMM256_CORE(Ab, 768, Bb, 768, 768)

#pragma unroll
    for (int mi = 0; mi < 8; ++mi) {
        const long long r = tM + wm * 128 + mi * 16 + rquad;
#pragma unroll
        for (int ni = 0; ni < 4; ++ni) {
            f32x4 v = acc[mi][ni];
            const long long c = tN + wn * 64 + ni * 16 + cl;
            const float bc = bias[c];
#pragma unroll
            for (int j = 0; j < 4; ++j)
                dst[(r + j) * 768 + c] = f2bf(v[j] + bc);
        }
    }
}

// ---- sexp: P~ = exp(scale*qp@kp^T) bf16. 128^2/BK64 core, (16,16,4) grid ----
__global__ __launch_bounds__(256, 2)
void sexp128(const ushort_t* __restrict__ qp, const ushort_t* __restrict__ kp,
             ushort_t* __restrict__ P, float scale)
{
    int bx, by, bz;
    xcd_remap(bx, by, bz);
    const long long tM = (long long)by * 128;
    const long long tN = (long long)bx * 128;
    const int z = bz;
    const ushort_t* Ab = qp + (long long)z * 1572864;
    const ushort_t* Bb = kp + (long long)z * 1572864;

    GEMM128_CORE(Ab, 768, Bb, 768, 12)

    ushort_t* out = P + (long long)z * 4194304;
#pragma unroll
    for (int mi = 0; mi < 4; ++mi) {
        const long long r = tM + wr * 64 + mi * 16 + rquad;
#pragma unroll
        for (int ni = 0; ni < 4; ++ni) {
            f32x4 v = acc[mi][ni];
            const long long c = tN + wc * 64 + ni * 16 + cl;
#pragma unroll
            for (int j = 0; j < 4; ++j)
                out[(r + j) * 2048 + c] = f2bf(__expf(v[j] * scale));
        }
    }
}

// ============================================================================
// PVN: O = (P @ Vp^T) / rowsum. 128x128 / BK=64 core, rowsum via ones-MFMA
// (rs4 accumulates in exactly the C-layout -> no shuffles/atomics).
// ============================================================================
__global__ __launch_bounds__(256, 2)
void pvn_rs(const ushort_t* __restrict__ Pg, const ushort_t* __restrict__ vpT,
            ushort_t* __restrict__ Og)
{
    int bx, by, bz;
    xcd_remap(bx, by, bz);
    const long long tM = (long long)by * 128;
    const long long tN = (long long)bx * 128;
    const int z = bz;
    const ushort_t* Ab = Pg + (long long)z * 4194304;   // P: [2048][2048] bf16
    const ushort_t* Bb = vpT + (long long)z * 2048;     // vpT: [768][8192], batch = col offset

    __shared__ __align__(16) ushort_t lds[2][2][128 * 64];   // 64 KB
    const int tid  = threadIdx.x;
    const int lane = tid & 63;
    const int wave = tid >> 6;
    const int wr = wave >> 1, wc = wave & 1;

    const u16x8 oneb = {0x3F80,0x3F80,0x3F80,0x3F80,0x3F80,0x3F80,0x3F80,0x3F80};
    const bf16x8 ones = __builtin_bit_cast(bf16x8, oneb);

    f32x4 acc[4][4];
    f32x4 rs4[4];
#pragma unroll
    for (int i = 0; i < 4; ++i) {
        rs4[i] = (f32x4){0.f, 0.f, 0.f, 0.f};
#pragma unroll
        for (int j = 0; j < 4; ++j)
            acc[i][j] = (f32x4){0.f, 0.f, 0.f, 0.f};
    }

    auto stage = [&](int buf, int kt) {
        const int k0 = kt * 64;
#pragma unroll
        for (int rnd = 0; rnd < 4; ++rnd) {
            const int idx  = rnd * 256 + tid;
            const int row  = idx >> 3;
            const int slot = idx & 7;
            const int ssrc = slot ^ (row & 7);
            const ushort_t* ga = Ab + (tM + row) * 2048LL + k0 + ssrc * 8;
            const ushort_t* gb = Bb + (tN + row) * 8192LL + k0 + ssrc * 8;
            __builtin_amdgcn_global_load_lds((const __attribute__((address_space(1))) void*)ga,
                                             (__attribute__((address_space(3))) void*)&lds[buf][0][idx * 8], 16, 0, 0);
            __builtin_amdgcn_global_load_lds((const __attribute__((address_space(1))) void*)gb,
                                             (__attribute__((address_space(3))) void*)&lds[buf][1][idx * 8], 16, 0, 0);
        }
    };
    auto compute = [&](int buf) {
        const int kbb = lane >> 4;
        const int r16 = lane & 15;
#pragma unroll
        for (int kk = 0; kk < 2; ++kk) {
            bf16x8 af[4], bfr[4];
#pragma unroll
            for (int mi = 0; mi < 4; ++mi) {
                const int row = wr * 64 + mi * 16 + r16;
                const int o16 = row * 8 + ((kk * 4 + kbb) ^ (row & 7));
                af[mi] = *(const bf16x8*)((const char*)lds[buf][0] + o16 * 16);
            }
#pragma unroll
            for (int ni = 0; ni < 4; ++ni) {
                const int row = wc * 64 + ni * 16 + r16;
                const int o16 = row * 8 + ((kk * 4 + kbb) ^ (row & 7));
                bfr[ni] = *(const bf16x8*)((const char*)lds[buf][1] + o16 * 16);
            }
            __builtin_amdgcn_s_setprio(1);
#pragma unroll
            for (int mi = 0; mi < 4; ++mi) {
#pragma unroll
                for (int ni = 0; ni < 4; ++ni)
                    acc[mi][ni] = __builtin_amdgcn_mfma_f32_16x16x32_bf16(af[mi], bfr[ni], acc[mi][ni], 0, 0, 0);
                rs4[mi] = __builtin_amdgcn_mfma_f32_16x16x32_bf16(af[mi], ones, rs4[mi], 0, 0, 0);
            }
            __builtin_amdgcn_s_setprio(0);
        }
    };

    stage(0, 0);
    __syncthreads();
    int cur = 0;
    for (int kt = 0; kt + 1 < 32; ++kt) {
        stage(cur ^ 1, kt + 1);
        compute(cur);
        __syncthreads();
        cur ^= 1;
    }
    compute(cur);

    const int rquad = (lane >> 4) * 4;
    const int cl    = lane & 15;
    ushort_t* out = Og + (long long)z * 1572864;
#pragma unroll
    for (int mi = 0; mi < 4; ++mi) {
        const long long r = tM + wr * 64 + mi * 16 + rquad;
        float inv[4];
#pragma unroll
        for (int j = 0; j < 4; ++j)
            inv[j] = 1.0f / rs4[mi][j];
#pragma unroll
        for (int ni = 0; ni < 4; ++ni) {
            f32x4 v = acc[mi][ni];
            const long long c = tN + wc * 64 + ni * 16 + cl;
#pragma unroll
            for (int j = 0; j < 4; ++j)
                out[(r + j) * 768 + c] = f2bf(v[j] * inv[j]);
        }
    }
}

// ---------------- OUT: fp32 = O @ Wp^T + bp, 128x128 / BK=64 core -----------
__global__ __launch_bounds__(256, 2)
void gemm_out(const ushort_t* __restrict__ A, const ushort_t* __restrict__ B,
              float* __restrict__ Cg, const float* __restrict__ bias)
{
    int bx, by, bz;
    xcd_remap(bx, by, bz);
    const long long tM = (long long)by * 128;
    const long long tN = (long long)bx * 128;
    const ushort_t* Ab = A;
    const ushort_t* Bb = B;

    GEMM128_CORE(Ab, 768, Bb, 768, 12)

#pragma unroll
    for (int mi = 0; mi < 4; ++mi) {
        const long long r = tM + wr * 64 + mi * 16 + rquad;
#pragma unroll
        for (int ni = 0; ni < 4; ++ni) {
            f32x4 v = acc[mi][ni];
            const long long c = tN + wc * 64 + ni * 16 + cl;
            const float bc = bias[c];
#pragma unroll
            for (int j = 0; j < 4; ++j)
                Cg[(r + j) * 768 + c] = v[j] + bc;
        }
    }
}

// ---------------- launch ----------------
extern "C" void kernel_launch(void* const* d_in, const int* in_sizes, int n_in,
                              void* d_out, int out_size, void* d_ws, size_t ws_size,
                              hipStream_t stream) {
    (void)in_sizes; (void)n_in; (void)out_size; (void)ws_size;
    const float* q  = (const float*)d_in[0];
    const float* k  = (const float*)d_in[1];
    const float* v  = (const float*)d_in[2];
    const float* Wq = (const float*)d_in[3];
    const float* bq = (const float*)d_in[4];
    const float* Wk = (const float*)d_in[5];
    const float* bk = (const float*)d_in[6];
    const float* Wv = (const float*)d_in[7];
    const float* bv = (const float*)d_in[8];
    const float* Wp = (const float*)d_in[9];
    const float* bp = (const float*)d_in[10];
    float* out = (float*)d_out;

    // ---- workspace layout (round-9 proven, no live-overlay) ----
    char* ws = (char*)d_ws;
    ushort_t* vb  = (ushort_t*)(ws);                 // [0, 12.6M)
    ushort_t* qb  = (ushort_t*)(ws + 12582912LL);
    ushort_t* kb  = (ushort_t*)(ws + 25165824LL);
    ushort_t* P   = (ushort_t*)(ws + 12582912LL);    // overlays dead qb,kb + gap
    ushort_t* Wqb = (ushort_t*)(ws + 46137344LL);
    ushort_t* Wkb = (ushort_t*)(ws + 47316992LL);
    ushort_t* Wvb = (ushort_t*)(ws + 48496640LL);
    ushort_t* Wpb = (ushort_t*)(ws + 49676288LL);
    ushort_t* qp  = (ushort_t*)(ws + 50855936LL);    // [8192][768] bf16
    ushort_t* kp  = (ushort_t*)(ws + 63438848LL);    // [8192][768] bf16
    ushort_t* vpT = (ushort_t*)(ws + 76021760LL);    // [768][8192] bf16
    ushort_t* Ob  = qp;                              // O overlays dead qp

    const float scale = 1.0f / sqrtf(768.0f);

    // 1) merged prep: cvt v + 4 weights
    cvt_all<<<8448, 256, 0, stream>>>(v, Wq, Wk, Wv, Wp, vb, Wqb, Wkb, Wvb, Wpb);

    // 2) fused: V-projection (96 tiles, 256^2 core) + cvt q,k (160 blocks)
    vprojcvt<<<256, 512, 0, stream>>>(Wvb, vb, bv, vpT, q, k, qb, kb);

    // 3) Q,K projections (192 tiles, 1 round)
    projqk2<<<dim3(3, 32, 2), 512, 0, stream>>>(qb, kb, Wqb, Wkb, bq, bk, qp, kp);

    // 4) P~ = exp(scale * QK^T)  (128^2/BK=64 structure, 1024 blocks, 2/CU)
    sexp128<<<dim3(16, 16, 4), 256, 0, stream>>>(qp, kp, P, scale);

    // 5) O = (P~ @ Vp^T) / rowsum   (rowsum via ones-MFMA; BK=64, 32 K-steps)
    pvn_rs<<<dim3(6, 16, 4), 256, 0, stream>>>(P, vpT, Ob);

    // 6) out = O @ Wp^T + bp  (BK=64, 12 K-steps)
    gemm_out<<<dim3(6, 64, 1), 256, 0, stream>>>(Ob, Wpb, out, bp);
}